// Round 5
// baseline (1010.960 us; speedup 1.0000x reference)
//
#include <hip/hip_runtime.h>

typedef __bf16 bf16;
typedef __bf16 bf16x8 __attribute__((ext_vector_type(8)));
typedef float f32x4 __attribute__((ext_vector_type(4)));

#define S_NB 50

// ---------------- weight pre-shuffle: f32 -> bf16 MFMA B-fragment layout ----
// For tower t (0..2), proj p in {1(K),2(V)}: mat = t*2 + (p-1).
// ws[mat*4096 + ((ks*4+nt)*64 + lane)*8 + e] =
//     bf16( gat_W[t][p][ ks*32 + (lane>>4)*8 + e ][ nt*16 + (lane&15) ] )
__global__ __launch_bounds__(256) void shuffle_w(const float* __restrict__ gatW,
                                                 bf16* __restrict__ ws) {
  int tid = blockIdx.x * 256 + threadIdx.x;
  if (tid >= 6 * 512) return;
  int mat = tid >> 9;
  int rem = tid & 511;
  int ks = rem >> 8;
  int nt = (rem >> 6) & 3;
  int lane = rem & 63;
  int t = mat >> 1, p = (mat & 1) + 1;
  const float* src = gatW + (size_t)(t * 4 + p) * 4096;
  int n = nt * 16 + (lane & 15);
  int kb = ks * 32 + (lane >> 4) * 8;
  bf16x8 v;
#pragma unroll
  for (int e = 0; e < 8; ++e) v[e] = (bf16)src[(kb + e) * 64 + n];
  *reinterpret_cast<bf16x8*>(ws + mat * 4096 + ((ks * 4 + nt) * 64 + lane) * 8) = v;
}

// ---------------- fused per-batch kernel ------------------------------------
struct Smem {
  float node[3 * 64];
  float qp[64];
  float sc[64];
  float eb[64];
  float yp[4 * 64];
  float y[64];
  float pp[4 * 64];
  float agg[2 * 64];
  float kvp[2 * 3 * 64];
};

// dst[n] = relu( sum_k src[k]*W[k][n] + bias[n] ), split-k over 4 waves. f32.
// NOTE: src/dst may point into the same __shared__ Smem as sm (disjoint
// members). No __restrict__ on any pointer that can alias LDS.
__device__ __forceinline__ void proj64(const float* src, const float* W,
                                       const float* bias, float* dst, Smem* sm,
                                       int wave, int lane, int tid) {
  float part = 0.f;
  const float* wp = W + wave * 16 * 64 + lane;
  const float* sp = src + wave * 16;
#pragma unroll
  for (int kk = 0; kk < 16; ++kk) part += sp[kk] * wp[kk * 64];
  sm->pp[wave * 64 + lane] = part;
  __syncthreads();
  if (tid < 64) {
    float v = sm->pp[tid] + sm->pp[64 + tid] + sm->pp[128 + tid] +
              sm->pp[192 + tid] + bias[tid];
    dst[tid] = fmaxf(v, 0.f);
  }
  __syncthreads();
}

__device__ __forceinline__ void gat_layer(
    int b, const int* idx, const float* table,
    const float* Wt,   // gatW + t*4*4096 (W0 at +0, W3 at +3*4096)
    const float* bt,   // gatB + t*256
    const bf16* frags, // ws + t*8192 (K-frags, then V-frags)
    const float* node, float* aggdst, Smem* sm, int wave, int lane, int tid) {
  // Neighbor id + A-fragment gathers (f32 rows -> bf16 fragments).
  int arow = wave * 16 + (lane & 15);
  int id = (arow < S_NB) ? idx[b * S_NB + arow] : 0; // row 0 of tables is zeros
  const float* rowp = table + (size_t)id * 64;
  int g = lane >> 4;
  float4 f0 = *reinterpret_cast<const float4*>(rowp + g * 8);
  float4 f1 = *reinterpret_cast<const float4*>(rowp + g * 8 + 4);
  float4 f2 = *reinterpret_cast<const float4*>(rowp + 32 + g * 8);
  float4 f3 = *reinterpret_cast<const float4*>(rowp + 32 + g * 8 + 4);
  bf16x8 a0, a1;
  a0[0] = (bf16)f0.x; a0[1] = (bf16)f0.y; a0[2] = (bf16)f0.z; a0[3] = (bf16)f0.w;
  a0[4] = (bf16)f1.x; a0[5] = (bf16)f1.y; a0[6] = (bf16)f1.z; a0[7] = (bf16)f1.w;
  a1[0] = (bf16)f2.x; a1[1] = (bf16)f2.y; a1[2] = (bf16)f2.z; a1[3] = (bf16)f2.w;
  a1[4] = (bf16)f3.x; a1[5] = (bf16)f3.y; a1[6] = (bf16)f3.z; a1[7] = (bf16)f3.w;

  // qp = relu(node @ W0 + b0)  (exact f32)
  proj64(node, Wt, bt, sm->qp, sm, wave, lane, tid);

  // kp/vp = relu(NB @ W{1,2} + b{1,2}) via bf16 MFMA; stay in registers (f32).
  f32x4 kacc[4], vacc[4];
#pragma unroll
  for (int nt = 0; nt < 4; ++nt) {
    kacc[nt] = f32x4{0.f, 0.f, 0.f, 0.f};
    vacc[nt] = f32x4{0.f, 0.f, 0.f, 0.f};
  }
  const bf16* fk = frags;
  const bf16* fv = frags + 4096;
#pragma unroll
  for (int nt = 0; nt < 4; ++nt) {
#pragma unroll
    for (int ks = 0; ks < 2; ++ks) {
      bf16x8 a = ks ? a1 : a0;
      bf16x8 bk = *reinterpret_cast<const bf16x8*>(fk + ((ks * 4 + nt) * 64 + lane) * 8);
      kacc[nt] = __builtin_amdgcn_mfma_f32_16x16x32_bf16(a, bk, kacc[nt], 0, 0, 0);
      bf16x8 bv = *reinterpret_cast<const bf16x8*>(fv + ((ks * 4 + nt) * 64 + lane) * 8);
      vacc[nt] = __builtin_amdgcn_mfma_f32_16x16x32_bf16(a, bv, vacc[nt], 0, 0, 0);
    }
  }
  const float* b1 = bt + 64;
  const float* b2 = bt + 128;
#pragma unroll
  for (int nt = 0; nt < 4; ++nt) {
    float kb = b1[nt * 16 + (lane & 15)];
    float vb = b2[nt * 16 + (lane & 15)];
#pragma unroll
    for (int e = 0; e < 4; ++e) {
      kacc[nt][e] = fmaxf(kacc[nt][e] + kb, 0.f);
      vacc[nt][e] = fmaxf(vacc[nt][e] + vb, 0.f);
    }
  }

  // scores[row] = dot(qp, kp[row]);  C-layout: row = wave*16+4*(lane>>4)+e,
  // col = nt*16 + (lane&15)
  float s[4] = {0.f, 0.f, 0.f, 0.f};
#pragma unroll
  for (int nt = 0; nt < 4; ++nt) {
    float qv = sm->qp[nt * 16 + (lane & 15)];
#pragma unroll
    for (int e = 0; e < 4; ++e) s[e] += kacc[nt][e] * qv;
  }
#pragma unroll
  for (int m = 1; m < 16; m <<= 1) {
#pragma unroll
    for (int e = 0; e < 4; ++e) s[e] += __shfl_xor(s[e], m, 64);
  }
  int rbase = wave * 16 + (lane >> 4) * 4;
  if ((lane & 15) == 0) {
#pragma unroll
    for (int e = 0; e < 4; ++e) sm->sc[rbase + e] = s[e];
  }
  __syncthreads();

  // softmax over 50 (scale 1/8 folded into exp)
  float mx = -1e30f;
  for (int i = 0; i < S_NB; ++i) mx = fmaxf(mx, sm->sc[i]);
  if (tid < 64) sm->eb[tid] = (tid < S_NB) ? __expf((sm->sc[tid] - mx) * 0.125f) : 0.f;
  __syncthreads();
  float den = 0.f;
  for (int i = 0; i < S_NB; ++i) den += sm->eb[i];
  float rden = 1.f / den;

  // y = sum_s a[s]*vp[s]; per-wave partial, reduce across waves in LDS.
  float ew[4];
#pragma unroll
  for (int e = 0; e < 4; ++e) ew[e] = sm->eb[rbase + e];
  float p[4];
#pragma unroll
  for (int nt = 0; nt < 4; ++nt) {
    p[nt] = ew[0] * vacc[nt][0] + ew[1] * vacc[nt][1] + ew[2] * vacc[nt][2] +
            ew[3] * vacc[nt][3];
    p[nt] += __shfl_xor(p[nt], 16, 64);
    p[nt] += __shfl_xor(p[nt], 32, 64);
  }
  if (lane < 16) {
#pragma unroll
    for (int nt = 0; nt < 4; ++nt) sm->yp[wave * 64 + nt * 16 + lane] = p[nt];
  }
  __syncthreads();
  if (tid < 64)
    sm->y[tid] = (sm->yp[tid] + sm->yp[64 + tid] + sm->yp[128 + tid] +
                  sm->yp[192 + tid]) * rden;
  __syncthreads();

  // agg = relu(y @ W3 + b3)
  proj64(sm->y, Wt + 3 * 4096, bt + 192, aggdst, sm, wave, lane, tid);
}

// keys: r==0 -> node, r>=1 -> agg + (r-1)*64
__device__ __forceinline__ void sem_layer(int ns, const float* node,
                                          const float* agg,
                                          const float* Wt, // semW + t*4*4096
                                          const float* bt, // semB + t*256
                                          float* outp, Smem* sm, int wave,
                                          int lane, int tid) {
  // qsem = relu(node @ W0 + b0)
  proj64(node, Wt, bt, sm->qp, sm, wave, lane, tid);

  // kp/vp rows: cells over (proj, row, col)
  for (int c = tid; c < 2 * ns * 64; c += 256) {
    int proj = c / (ns * 64);
    int r = (c >> 6) % ns;
    int n = c & 63;
    const float* w = Wt + (size_t)(proj + 1) * 4096;
    const float* src = (r == 0) ? node : (agg + (r - 1) * 64);
    float acc = bt[(proj + 1) * 64 + n];
#pragma unroll 8
    for (int k = 0; k < 64; ++k) acc += src[k] * w[k * 64 + n];
    sm->kvp[(proj * 3 + r) * 64 + n] = fmaxf(acc, 0.f);
  }
  __syncthreads();
  if (tid < ns) {
    float acc = 0.f;
#pragma unroll 8
    for (int k = 0; k < 64; ++k) acc += sm->qp[k] * sm->kvp[tid * 64 + k];
    sm->sc[tid] = acc * 0.125f;
  }
  __syncthreads();
  // softmax over ns (redundant per thread) + y
  float mx = sm->sc[0];
  for (int i = 1; i < ns; ++i) mx = fmaxf(mx, sm->sc[i]);
  float e0 = __expf(sm->sc[0] - mx);
  float e1 = __expf(sm->sc[1] - mx);
  float e2 = (ns > 2) ? __expf(sm->sc[2] - mx) : 0.f;
  float rden = 1.f / (e0 + e1 + e2);
  if (tid < 64) {
    float yv = e0 * sm->kvp[(3 + 0) * 64 + tid] + e1 * sm->kvp[(3 + 1) * 64 + tid];
    if (ns > 2) yv += e2 * sm->kvp[(3 + 2) * 64 + tid];
    sm->y[tid] = yv * rden;
  }
  __syncthreads();
  // out = relu(y @ W3 + b3) -> global f32
  float part = 0.f;
  const float* wp = Wt + 3 * 4096 + wave * 16 * 64 + lane;
#pragma unroll
  for (int kk = 0; kk < 16; ++kk) part += sm->y[wave * 16 + kk] * wp[kk * 64];
  sm->pp[wave * 64 + lane] = part;
  __syncthreads();
  if (tid < 64) {
    float v = sm->pp[tid] + sm->pp[64 + tid] + sm->pp[128 + tid] +
              sm->pp[192 + tid] + bt[192 + tid];
    outp[tid] = fmaxf(v, 0.f);
  }
  __syncthreads();
}

__global__ __launch_bounds__(256) void fused_towers(
    const int* __restrict__ uids, const int* __restrict__ qids,
    const int* __restrict__ mids, const int* __restrict__ u_movies,
    const int* __restrict__ m_querys, const int* __restrict__ m_users,
    const int* __restrict__ q_movies, const float* __restrict__ user_t,
    const float* __restrict__ item_t, const float* __restrict__ query_t,
    const float* __restrict__ gatW, const float* __restrict__ gatB,
    const float* __restrict__ semW, const float* __restrict__ semB,
    const bf16* __restrict__ wfrag, float* __restrict__ out) {
  __shared__ Smem sm;
  int b = blockIdx.x;
  int tid = threadIdx.x;
  int lane = tid & 63;
  int wave = tid >> 6;

  // node rows (u, m, q) -> f32 LDS
  if (tid < 192) {
    int tower = tid >> 6, n = tid & 63;
    int id = (tower == 0) ? uids[b] : (tower == 1 ? mids[b] : qids[b]);
    const float* tab = (tower == 0) ? user_t : (tower == 1 ? item_t : query_t);
    sm.node[tower * 64 + n] = tab[(size_t)id * 64 + n];
  }
  __syncthreads();

  float* outb = out + (size_t)b * 192;

  // ---- Tower U (t=0) ----
  gat_layer(b, u_movies, item_t, gatW, gatB, wfrag, sm.node, sm.agg, &sm, wave, lane, tid);
  sem_layer(2, sm.node, sm.agg, semW, semB, outb, &sm, wave, lane, tid);

  // ---- Tower M (t=1) ----
  gat_layer(b, m_querys, query_t, gatW + 4 * 4096, gatB + 256, wfrag + 8192,
            sm.node + 64, sm.agg, &sm, wave, lane, tid);
  gat_layer(b, m_users, user_t, gatW + 4 * 4096, gatB + 256, wfrag + 8192,
            sm.node + 64, sm.agg + 64, &sm, wave, lane, tid);
  sem_layer(3, sm.node + 64, sm.agg, semW + 4 * 4096, semB + 256, outb + 64, &sm,
            wave, lane, tid);

  // ---- Tower Q (t=2) ----
  gat_layer(b, q_movies, item_t, gatW + 8 * 4096, gatB + 512, wfrag + 16384,
            sm.node + 128, sm.agg, &sm, wave, lane, tid);
  sem_layer(2, sm.node + 128, sm.agg, semW + 8 * 4096, semB + 512, outb + 128, &sm,
            wave, lane, tid);
}

extern "C" void kernel_launch(void* const* d_in, const int* in_sizes, int n_in,
                              void* d_out, int out_size, void* d_ws, size_t ws_size,
                              hipStream_t stream) {
  const int* uids = (const int*)d_in[0];
  const int* qids = (const int*)d_in[1];
  const int* mids = (const int*)d_in[2];
  const int* u_movies = (const int*)d_in[3];
  const int* m_querys = (const int*)d_in[4];
  const int* m_users = (const int*)d_in[5];
  const int* q_movies = (const int*)d_in[6];
  const float* user_t = (const float*)d_in[7];
  const float* item_t = (const float*)d_in[8];
  const float* query_t = (const float*)d_in[9];
  const float* gatW = (const float*)d_in[10];
  const float* gatB = (const float*)d_in[11];
  const float* semW = (const float*)d_in[12];
  const float* semB = (const float*)d_in[13];
  float* out = (float*)d_out;
  bf16* wfrag = (bf16*)d_ws; // needs 6*4096*2 = 48 KiB

  int B = in_sizes[0];
  shuffle_w<<<12, 256, 0, stream>>>(gatW, wfrag);
  fused_towers<<<B, 256, 0, stream>>>(uids, qids, mids, u_movies, m_querys,
                                      m_users, q_movies, user_t, item_t, query_t,
                                      gatW, gatB, semW, semB, wfrag, out);
}